// Round 18
// baseline (151.185 us; speedup 1.0000x reference)
//
#include <hip/hip_runtime.h>
#include <hip/hip_bf16.h>

#define NN 16384          // sequence length
#define NC 16             // layer channels
#define NPOSTOT 131072    // 8 * 16384
#define NLAY 29           // gated layers
#define TOUT 256          // output positions per block
#define LSTR 24           // LDS row stride in shorts (48 B -> bank-uniform)

typedef float4 f4;
typedef short bf16x8 __attribute__((ext_vector_type(8)));
typedef float f32x4 __attribute__((ext_vector_type(4)));

// prepack element offsets (in shorts)
#define OFF_WF 0
#define OFF_WG (NLAY * 512)
#define OFF_WR (2 * NLAY * 512)
#define OFF_WA (3 * NLAY * 512)
#define OFF_WO (3 * NLAY * 512 + 2048)
#define PK_TOT (OFF_WO + 16384)

static __device__ __forceinline__ short to_bf16(float f) {
    __hip_bfloat16 h = __float2bfloat16(f);   // RNE
    short s;
    __builtin_memcpy(&s, &h, 2);
    return s;
}
static __device__ __forceinline__ float from_bf16(short s) {
    unsigned int u = ((unsigned int)(unsigned short)s) << 16;
    float f;
    __builtin_memcpy(&f, &u, 4);
    return f;
}

// ---------------- weight prepack into MFMA A-fragments (bf16) -----------------
// Slot-consistency: A and B packed with the same (h=lane>>4, j)->k bijection.
//  conv (K=32):  k = h*8+j ; tap = k>>4, c = k&15           (B from memory)
//  1x1  (K=32):  j<4 -> k = h*4+j (=channel), j>=4 -> zero  (B = conv output)
//  Wa   (K=32):  k = h*8+j, real for k<16 (c=k), else zero  (B from memory)
//  Wo   (K=64):  half hf, k = hf*32 + (j>>2)*16 + h*4 + (j&3)  (B = Wa output)
__global__ __launch_bounds__(256) void prepack_k(
    const float* __restrict__ Wf, const float* __restrict__ Wg,
    const float* __restrict__ Wr, const float* __restrict__ Wa,
    const float* __restrict__ Wo, short* __restrict__ pk)
{
    const int i = blockIdx.x * 256 + threadIdx.x;
    if (i >= PK_TOT) return;
    float val;
    if (i < OFF_WG) {                               // Wf frags
        const int j = i >> 9, r = i & 511, l = r >> 3, j8 = r & 7;
        const int o = l & 15, h = l >> 4;
        const int k = h * 8 + j8, tap = k >> 4, c = k & 15;
        val = Wf[((j * 16 + o) * 16 + c) * 2 + tap];
    } else if (i < OFF_WA) {
        const int i2 = i - OFF_WG;
        if (i2 < NLAY * 512) {                      // Wg frags
            const int j = i2 >> 9, r = i2 & 511, l = r >> 3, j8 = r & 7;
            const int o = l & 15, h = l >> 4;
            const int k = h * 8 + j8, tap = k >> 4, c = k & 15;
            val = Wg[((j * 16 + o) * 16 + c) * 2 + tap];
        } else {                                    // Wr frags (half zero-padded)
            const int i3 = i2 - NLAY * 512;
            const int j = i3 >> 9, r = i3 & 511, l = r >> 3, j8 = r & 7;
            const int o = l & 15, h = l >> 4;
            val = (j8 < 4) ? Wr[j * 256 + o * 16 + h * 4 + j8] : 0.0f;
        }
    } else if (i < OFF_WO) {                        // Wa frags (4 m-tiles)
        const int i2 = i - OFF_WA;
        const int mt = i2 >> 9, r = i2 & 511, l = r >> 3, j8 = r & 7;
        const int og = mt * 16 + (l & 15), h = l >> 4;
        const int k = h * 8 + j8;
        val = (k < 16) ? Wa[og * 16 + k] : 0.0f;
    } else {                                        // Wo frags (16 q-tiles x 2 halves)
        const int i2 = i - OFF_WO;
        const int qt = i2 >> 10, hf = (i2 >> 9) & 1, r = i2 & 511;
        const int l = r >> 3, j8 = r & 7;
        const int q = qt * 16 + (l & 15), h = l >> 4;
        const int kg = hf * 32 + (j8 >> 2) * 16 + h * 4 + (j8 & 3);
        val = Wo[q * 64 + kg];
    }
    pk[i] = to_bf16(val);
}

// ---------------- gated MFMA core: 2 conv MFMA + merged act + 1x1 MFMA -------
static __device__ __forceinline__ f32x4 gated_core2(
    bf16x8 bx, bf16x8 af_, bf16x8 ag_, bf16x8 ar_,
    f32x4 cf, f32x4 cg, f32x4 cr)
{
    const f32x4 fp = __builtin_amdgcn_mfma_f32_16x16x32_bf16(af_, bx, cf, 0, 0, 0);
    const f32x4 gp = __builtin_amdgcn_mfma_f32_16x16x32_bf16(ag_, bx, cg, 0, 0, 0);

    bf16x8 bz;
#pragma unroll
    for (int r = 0; r < 4; ++r) {
        // z = tanh(f)*sigmoid(g) = (e^{2f}-1) / ((e^{2f}+1)(1+e^{-g}))
        const float ef = __expf(2.0f * fminf(fp[r], 43.0f));   // clamp: no inf
        const float eg = __expf(-gp[r]);
        const float den = fmaf(ef, eg, ef) + (eg + 1.0f);
        bz[r] = to_bf16((ef - 1.0f) * __builtin_amdgcn_rcpf(den));
        bz[r + 4] = 0;
    }
    return __builtin_amdgcn_mfma_f32_16x16x32_bf16(ar_, bz, cr, 0, 0, 0);
}

// ---------------- fused multi-layer segment kernel (R17 + frag prefetch) ------
// 7-dispatch schedule; NEW (isolated from R7): weight fragments + biases for
// layer s+1 are loaded at the top of iteration s, so their global-load latency
// hides under layer s's MFMA/trans compute instead of serializing after the
// barrier at the head of layer s+1.
struct SegCfg { int d[8]; int nl; int jbase; int H; int l0; };

constexpr SegCfg CFGS[7] = {
    {{2, 4, 8, 16, 32, 64, 0, 0},     6, 0,  128, 1},  // K0: L0 + j0..j5
    {{128, 256, 0, 0, 0, 0, 0, 0},    2, 6,  256, 0},  // K1: j6,j7
    {{512, 1, 2, 4, 8, 16, 32, 64},   8, 8,  128, 0},  // K2: j8..j15
    {{128, 256, 0, 0, 0, 0, 0, 0},    2, 16, 256, 0},  // K3: j16,j17
    {{512, 1, 2, 4, 8, 16, 32, 64},   8, 18, 128, 0},  // K4: j18..j25
    {{128, 256, 0, 0, 0, 0, 0, 0},    2, 26, 256, 0},  // K5: j26,j27
    {{512, 0, 0, 0, 0, 0, 0, 0},      1, 28, 0,   0},  // K6: j28
};

#define LDF(J, AF, AG, AR, CF, CG, CR) do {                               \
    AF = *(const bf16x8*)(pk + OFF_WF + (J) * 512 + lane * 8);            \
    AG = *(const bf16x8*)(pk + OFF_WG + (J) * 512 + lane * 8);            \
    AR = *(const bf16x8*)(pk + OFF_WR + (J) * 512 + lane * 8);            \
    const f4 v1_ = *(const f4*)(bfA + (J) * 16 + h * 4);                  \
    const f4 v2_ = *(const f4*)(bgA + (J) * 16 + h * 4);                  \
    const f4 v3_ = *(const f4*)(brA + (J) * 16 + h * 4);                  \
    CF[0] = v1_.x; CF[1] = v1_.y; CF[2] = v1_.z; CF[3] = v1_.w;           \
    CG[0] = v2_.x; CG[1] = v2_.y; CG[2] = v2_.z; CG[3] = v2_.w;           \
    CR[0] = v3_.x; CR[1] = v3_.y; CR[2] = v3_.z; CR[3] = v3_.w;           \
} while (0)

template<int KI>
__global__ __launch_bounds__((TOUT + CFGS[KI].H) * 2)
void fused_t(const short* __restrict__ src, const float* __restrict__ x,
             const float* __restrict__ W0, const float* __restrict__ b0,
             short* __restrict__ dst, const short* __restrict__ pk,
             const float* __restrict__ bfA, const float* __restrict__ bgA,
             const float* __restrict__ brA)
{
    constexpr SegCfg cfg = CFGS[KI];
    constexpr int H = cfg.H;
    constexpr int Wp = TOUT + H;
    constexpr bool MULTI = (cfg.nl > 1);
    constexpr int LDSSZ = MULTI ? 2 * Wp * LSTR : 8;
    __shared__ short lds[LDSSZ];
    short* ldsA = lds;
    short* ldsB = lds + (MULTI ? Wp * LSTR : 0);

    const int t = threadIdx.x, lane = t & 63, wv = t >> 6;
    const int h = lane >> 4, i16 = lane & 15;
    const int tap = h >> 1, c0 = (h & 1) * 8;
    const int pbase = blockIdx.x * TOUT;
    const int bb = pbase >> 14, n0 = pbase & (NN - 1);
    const float* xrow = x + (size_t)bb * NN;
    const short* srow = src + (size_t)bb * NN * NC;

    const int l0r = wv * 32 + i16;     // this wave's tile-0 row in LDS coords
    const int l1r = l0r + 16;          // tile-1 row
    const int nA = n0 - H + l0r;       // sequence positions
    const int nB = nA + 16;

    f32x4 res0, res1;                  // fp32 residual, lives in VGPRs

    bf16x8 afN, agN, arN;              // prefetched frags for the NEXT layer
    f32x4 cfN, cgN, crN;

    // ---- phase 0: first layer of the group, inputs from GLOBAL (no halo) ----
    {
        constexpr int d = cfg.d[0];
        constexpr int j = cfg.jbase;
        bf16x8 af, ag, ar;
        f32x4 cf, cg, cr;
        LDF(j, af, ag, ar, cf, cg, cr);
        if constexpr (MULTI)           // prefetch layer 1 under phase-0 compute
            LDF(j + 1, afN, agN, arN, cfN, cgN, crN);

        auto tile0 = [&](int l, int n, f32x4& res) {
            const int ns = tap ? n : n - d;
            bf16x8 bx = {0, 0, 0, 0, 0, 0, 0, 0};
            if (cfg.l0) {
                if (ns >= 0) {   // layer-0 output computed on the fly from x
                    const float xs = xrow[ns] * (1.0f / 32768.0f);
                    const float xm = (ns >= 1) ? xrow[ns - 1] * (1.0f / 32768.0f) : 0.0f;
#pragma unroll
                    for (int q2 = 0; q2 < 8; ++q2) {
                        const int c = c0 + q2;
                        bx[q2] = to_bf16(xs + fmaf(W0[c * 2], xm,
                                          fmaf(W0[c * 2 + 1], xs, b0[c])));
                    }
                }
            } else {
                if (ns >= 0) bx = *(const bf16x8*)(srow + (size_t)ns * NC + c0);
            }
            const f32x4 o = gated_core2(bx, af, ag, ar, cf, cg, cr);

            float r0, r1, r2, r3;        // residual input at (n, h*4..h*4+3)
            if (cfg.l0) {
                if (n >= 0) {
                    const float xs = xrow[n] * (1.0f / 32768.0f);
                    const float xm = (n >= 1) ? xrow[n - 1] * (1.0f / 32768.0f) : 0.0f;
                    const int c = h * 4;
                    r0 = xs + fmaf(W0[c * 2 + 0], xm, fmaf(W0[c * 2 + 1], xs, b0[c + 0]));
                    r1 = xs + fmaf(W0[c * 2 + 2], xm, fmaf(W0[c * 2 + 3], xs, b0[c + 1]));
                    r2 = xs + fmaf(W0[c * 2 + 4], xm, fmaf(W0[c * 2 + 5], xs, b0[c + 2]));
                    r3 = xs + fmaf(W0[c * 2 + 6], xm, fmaf(W0[c * 2 + 7], xs, b0[c + 3]));
                } else { r0 = r1 = r2 = r3 = 0.0f; }
            } else {
                if (n >= 0) {
                    const short4 ov = *(const short4*)(srow + (size_t)n * NC + h * 4);
                    r0 = from_bf16(ov.x); r1 = from_bf16(ov.y);
                    r2 = from_bf16(ov.z); r3 = from_bf16(ov.w);
                } else { r0 = r1 = r2 = r3 = 0.0f; }
            }
            res[0] = r0 + o[0]; res[1] = r1 + o[1];
            res[2] = r2 + o[2]; res[3] = r3 + o[3];
            if (MULTI) {
                *(short4*)(ldsA + l * LSTR + h * 4) =
                    make_short4(to_bf16(res[0]), to_bf16(res[1]),
                                to_bf16(res[2]), to_bf16(res[3]));
            }
        };
        tile0(l0r, nA, res0);
        tile0(l1r, nB, res1);
    }
    if (MULTI) __syncthreads();

    // ---- layers 1..nl-1: taps from LDS; frags for s+1 prefetched during s ----
    int cur = 0;
#pragma unroll
    for (int s = 1; s < cfg.nl; ++s) {
        const int d = cfg.d[s];
        const bf16x8 af = afN, ag = agN, ar = arN;   // consume prefetched set
        const f32x4 cf = cfN, cg = cgN, cr = crN;
        if (s + 1 < cfg.nl)                          // issue next-layer loads now
            LDF(cfg.jbase + s + 1, afN, agN, arN, cfN, cgN, crN);
        const short* rb = cur ? ldsB : ldsA;
        short* wb = cur ? ldsA : ldsB;
        const bool wr = (s + 1 < cfg.nl);   // last layer: LDS write is dead

        auto tileL = [&](int l, int n, f32x4& res) {
            const int nt = tap ? n : n - d;
            int lt = tap ? l : l - d;
            if (lt < 0) lt = 0;          // garbage-region clamp (never read clean)
            bf16x8 bx = {0, 0, 0, 0, 0, 0, 0, 0};
            if (nt >= 0) bx = *(const bf16x8*)(rb + lt * LSTR + c0);
            const f32x4 o = gated_core2(bx, af, ag, ar, cf, cg, cr);
            res[0] += o[0]; res[1] += o[1]; res[2] += o[2]; res[3] += o[3];
            if (wr) {
                *(short4*)(wb + l * LSTR + h * 4) =
                    make_short4(to_bf16(res[0]), to_bf16(res[1]),
                                to_bf16(res[2]), to_bf16(res[3]));
            }
        };
        tileL(l0r, nA, res0);
        tileL(l1r, nB, res1);
        if (s + 1 < cfg.nl) __syncthreads();
        cur ^= 1;
    }

    // ---- writeback of owned positions from registers ----
    if (l0r >= H) {
        *(short4*)(dst + ((size_t)bb * NN + nA) * NC + h * 4) =
            make_short4(to_bf16(res0[0]), to_bf16(res0[1]),
                        to_bf16(res0[2]), to_bf16(res0[3]));
    }
    if (l1r >= H) {
        *(short4*)(dst + ((size_t)bb * NN + nB) * NC + h * 4) =
            make_short4(to_bf16(res1[0]), to_bf16(res1[1]),
                        to_bf16(res1[2]), to_bf16(res1[3]));
    }
}

// ---------------- head: Wo frags in LDS; 512 threads, direct stores -----------
// (R12 version: static lg indexing keeps logits in VGPRs; 64B lines/h-group.)
__global__ __launch_bounds__(512, 2) void headm_k(
    const short* __restrict__ fin, const float* __restrict__ x,
    const int* __restrict__ lengths,
    const short* __restrict__ pka, const float* __restrict__ ba,
    const short* __restrict__ pko, const float* __restrict__ bo,
    float* __restrict__ out)
{
    __shared__ short ldsW[16384];            // all Wo fragments, 32 KB

    const int t = threadIdx.x;
    const int lane = t & 63;
    const int wv = t >> 6;
    const int i16 = lane & 15;
    const int h = lane >> 4;
    const int pos = blockIdx.x * 128 + wv * 16 + i16;
    const int b = pos >> 14;
    const int n = pos & (NN - 1);

    // cooperative stage of Wo frags: 512 threads x 4 x 16B coalesced
#pragma unroll
    for (int i = 0; i < 4; ++i)
        ((f4*)ldsW)[t + i * 512] = ((const f4*)pko)[t + i * 512];

    // B fragment for Wa: sk = relu(fin - xs), channels k=h*8+j (real for h<2)
    bf16x8 bs;
    if (h < 2) {
        const float xs = x[pos] * (1.0f / 32768.0f);
        const bf16x8 v = *(const bf16x8*)(fin + (size_t)pos * NC + h * 8);
#pragma unroll
        for (int j = 0; j < 8; ++j)
            bs[j] = to_bf16(fmaxf(from_bf16(v[j]) - xs, 0.0f));
    } else {
#pragma unroll
        for (int j = 0; j < 8; ++j) bs[j] = 0;
    }

    // Wa GEMM: ra = relu(...), 16 values/lane, lane-local for Wo B-frags
    float ra[16];
#pragma unroll
    for (int mt = 0; mt < 4; ++mt) {
        const bf16x8 aa = *(const bf16x8*)(pka + (mt * 64 + lane) * 8);
        const f4 bav = *(const f4*)(ba + mt * 16 + h * 4);
        f32x4 c = {bav.x, bav.y, bav.z, bav.w};
        c = __builtin_amdgcn_mfma_f32_16x16x32_bf16(aa, bs, c, 0, 0, 0);
#pragma unroll
        for (int r = 0; r < 4; ++r) ra[mt * 4 + r] = fmaxf(c[r], 0.0f);
    }
    bf16x8 blo, bhi;
#pragma unroll
    for (int j = 0; j < 8; ++j) { blo[j] = to_bf16(ra[j]); bhi[j] = to_bf16(ra[8 + j]); }

    __syncthreads();   // Wo frags staged

    // Wo GEMM: 16 q-tiles x (2 MFMA, K=64); A-frags from LDS; logits in VGPRs
    float lg[64];
#pragma unroll
    for (int qt = 0; qt < 16; ++qt) {
        const bf16x8 a0 = *(const bf16x8*)(ldsW + ((qt * 2 + 0) * 64 + lane) * 8);
        const bf16x8 a1 = *(const bf16x8*)(ldsW + ((qt * 2 + 1) * 64 + lane) * 8);
        const f4 bov = *(const f4*)(bo + qt * 16 + h * 4);
        f32x4 c = {bov.x, bov.y, bov.z, bov.w};
        c = __builtin_amdgcn_mfma_f32_16x16x32_bf16(a0, blo, c, 0, 0, 0);
        c = __builtin_amdgcn_mfma_f32_16x16x32_bf16(a1, bhi, c, 0, 0, 0);
#pragma unroll
        for (int r = 0; r < 4; ++r) lg[qt * 4 + r] = c[r];
    }

    // LSE across lanes {i, i+16, i+32, i+48}
    float m = lg[0];
#pragma unroll
    for (int j = 1; j < 64; ++j) m = fmaxf(m, lg[j]);
    m = fmaxf(m, __shfl_xor(m, 16, 64));
    m = fmaxf(m, __shfl_xor(m, 32, 64));
    float s = 0.0f;
#pragma unroll
    for (int j = 0; j < 64; ++j) s += __expf(lg[j] - m);
    s += __shfl_xor(s, 16, 64);
    s += __shfl_xor(s, 32, 64);
    const float lse = m + __logf(s);
    const bool valid = n < lengths[b];

    // write: q = qt*16 + h*4 + r at out[b][q][n] (full 64B lines per h-group)
    float* ob = out + (size_t)b * 256 * NN + n;
#pragma unroll
    for (int qt = 0; qt < 16; ++qt)
#pragma unroll
        for (int r = 0; r < 4; ++r)
            ob[(size_t)(qt * 16 + h * 4 + r) * NN] = valid ? (lg[qt * 4 + r] - lse) : 0.0f;
}

extern "C" void kernel_launch(void* const* d_in, const int* in_sizes, int n_in,
                              void* d_out, int out_size, void* d_ws, size_t ws_size,
                              hipStream_t stream)
{
    const float* x       = (const float*)d_in[0];
    const int*   lengths = (const int*)d_in[1];
    const float* W0      = (const float*)d_in[2];
    const float* b0      = (const float*)d_in[3];
    const float* Wf      = (const float*)d_in[4];
    const float* bf      = (const float*)d_in[5];
    const float* Wg      = (const float*)d_in[6];
    const float* bg      = (const float*)d_in[7];
    const float* Wr      = (const float*)d_in[8];
    const float* br      = (const float*)d_in[9];
    const float* Wa      = (const float*)d_in[10];
    const float* ba      = (const float*)d_in[11];
    const float* Wo      = (const float*)d_in[12];
    const float* bo      = (const float*)d_in[13];
    float* out = (float*)d_out;

    short* bufA = (short*)d_ws;                         // (B,N,16) bf16, 4.2 MB
    short* bufB = bufA + (size_t)NPOSTOT * NC;
    short* pk   = bufB + (size_t)NPOSTOT * NC;          // packed weight frags

    prepack_k<<<dim3((PK_TOT + 255) / 256), dim3(256), 0, stream>>>(
        Wf, Wg, Wr, Wa, Wo, pk);

#define FUSED(K, SRC, DST)                                                     \
    fused_t<K><<<dim3(NPOSTOT / TOUT), dim3((TOUT + CFGS[K].H) * 2), 0,        \
                 stream>>>(SRC, x, W0, b0, DST, pk, bf, bg, br)

    FUSED(0, bufA, bufA);   // src unused (l0 mode)
    FUSED(1, bufA, bufB);
    FUSED(2, bufB, bufA);
    FUSED(3, bufA, bufB);
    FUSED(4, bufB, bufA);
    FUSED(5, bufA, bufB);
    FUSED(6, bufB, bufA);
#undef FUSED

    headm_k<<<dim3(NPOSTOT / 128), dim3(512), 0, stream>>>(
        bufA, x, lengths, pk + OFF_WA, ba, pk + OFF_WO, bo, out);
}

// Round 19
// 136.182 us; speedup vs baseline: 1.1102x; 1.1102x over previous
//
#include <hip/hip_runtime.h>
#include <hip/hip_bf16.h>

#define NN 16384          // sequence length
#define NC 16             // layer channels
#define NPOSTOT 131072    // 8 * 16384
#define NLAY 29           // gated layers
#define TOUT 256          // output positions per block
#define LSTR 24           // LDS row stride in shorts (48 B -> bank-uniform)

typedef float4 f4;
typedef short bf16x8 __attribute__((ext_vector_type(8)));
typedef float f32x4 __attribute__((ext_vector_type(4)));

// prepack element offsets (in shorts)
#define OFF_WF 0
#define OFF_WG (NLAY * 512)
#define OFF_WR (2 * NLAY * 512)
#define OFF_WA (3 * NLAY * 512)
#define OFF_WO (3 * NLAY * 512 + 2048)
#define PK_TOT (OFF_WO + 16384)

static __device__ __forceinline__ short to_bf16(float f) {
    __hip_bfloat16 h = __float2bfloat16(f);   // RNE
    short s;
    __builtin_memcpy(&s, &h, 2);
    return s;
}
static __device__ __forceinline__ float from_bf16(short s) {
    unsigned int u = ((unsigned int)(unsigned short)s) << 16;
    float f;
    __builtin_memcpy(&f, &u, 4);
    return f;
}

// ---------------- weight prepack into MFMA A-fragments (bf16) -----------------
// Slot-consistency: A and B packed with the same (h=lane>>4, j)->k bijection.
//  conv (K=32):  k = h*8+j ; tap = k>>4, c = k&15           (B from memory)
//  1x1  (K=32):  j<4 -> k = h*4+j (=channel), j>=4 -> zero  (B = conv output)
//  Wa   (K=32):  k = h*8+j, real for k<16 (c=k), else zero  (B from memory)
//  Wo   (K=64):  half hf, k = hf*32 + (j>>2)*16 + h*4 + (j&3)  (B = Wa output)
__global__ __launch_bounds__(256) void prepack_k(
    const float* __restrict__ Wf, const float* __restrict__ Wg,
    const float* __restrict__ Wr, const float* __restrict__ Wa,
    const float* __restrict__ Wo, short* __restrict__ pk)
{
    const int i = blockIdx.x * 256 + threadIdx.x;
    if (i >= PK_TOT) return;
    float val;
    if (i < OFF_WG) {                               // Wf frags
        const int j = i >> 9, r = i & 511, l = r >> 3, j8 = r & 7;
        const int o = l & 15, h = l >> 4;
        const int k = h * 8 + j8, tap = k >> 4, c = k & 15;
        val = Wf[((j * 16 + o) * 16 + c) * 2 + tap];
    } else if (i < OFF_WA) {
        const int i2 = i - OFF_WG;
        if (i2 < NLAY * 512) {                      // Wg frags
            const int j = i2 >> 9, r = i2 & 511, l = r >> 3, j8 = r & 7;
            const int o = l & 15, h = l >> 4;
            const int k = h * 8 + j8, tap = k >> 4, c = k & 15;
            val = Wg[((j * 16 + o) * 16 + c) * 2 + tap];
        } else {                                    // Wr frags (half zero-padded)
            const int i3 = i2 - NLAY * 512;
            const int j = i3 >> 9, r = i3 & 511, l = r >> 3, j8 = r & 7;
            const int o = l & 15, h = l >> 4;
            val = (j8 < 4) ? Wr[j * 256 + o * 16 + h * 4 + j8] : 0.0f;
        }
    } else if (i < OFF_WO) {                        // Wa frags (4 m-tiles)
        const int i2 = i - OFF_WA;
        const int mt = i2 >> 9, r = i2 & 511, l = r >> 3, j8 = r & 7;
        const int og = mt * 16 + (l & 15), h = l >> 4;
        const int k = h * 8 + j8;
        val = (k < 16) ? Wa[og * 16 + k] : 0.0f;
    } else {                                        // Wo frags (16 q-tiles x 2 halves)
        const int i2 = i - OFF_WO;
        const int qt = i2 >> 10, hf = (i2 >> 9) & 1, r = i2 & 511;
        const int l = r >> 3, j8 = r & 7;
        const int q = qt * 16 + (l & 15), h = l >> 4;
        const int kg = hf * 32 + (j8 >> 2) * 16 + h * 4 + (j8 & 3);
        val = Wo[q * 64 + kg];
    }
    pk[i] = to_bf16(val);
}

// ---------------- gated MFMA core: 2 conv MFMA + merged act + 1x1 MFMA -------
static __device__ __forceinline__ f32x4 gated_core2(
    bf16x8 bx, bf16x8 af_, bf16x8 ag_, bf16x8 ar_,
    f32x4 cf, f32x4 cg, f32x4 cr)
{
    const f32x4 fp = __builtin_amdgcn_mfma_f32_16x16x32_bf16(af_, bx, cf, 0, 0, 0);
    const f32x4 gp = __builtin_amdgcn_mfma_f32_16x16x32_bf16(ag_, bx, cg, 0, 0, 0);

    bf16x8 bz;
#pragma unroll
    for (int r = 0; r < 4; ++r) {
        // z = tanh(f)*sigmoid(g) = (e^{2f}-1) / ((e^{2f}+1)(1+e^{-g}))
        const float ef = __expf(2.0f * fminf(fp[r], 43.0f));   // clamp: no inf
        const float eg = __expf(-gp[r]);
        const float den = fmaf(ef, eg, ef) + (eg + 1.0f);
        bz[r] = to_bf16((ef - 1.0f) * __builtin_amdgcn_rcpf(den));
        bz[r + 4] = 0;
    }
    return __builtin_amdgcn_mfma_f32_16x16x32_bf16(ar_, bz, cr, 0, 0, 0);
}

// ---------------- fused multi-layer segment kernel (R17, unchanged) -----------
// 6-dispatch schedule: j28 moved into the head.
struct SegCfg { int d[8]; int nl; int jbase; int H; int l0; };

constexpr SegCfg CFGS[6] = {
    {{2, 4, 8, 16, 32, 64, 0, 0},     6, 0,  128, 1},  // K0: L0 + j0..j5
    {{128, 256, 0, 0, 0, 0, 0, 0},    2, 6,  256, 0},  // K1: j6,j7
    {{512, 1, 2, 4, 8, 16, 32, 64},   8, 8,  128, 0},  // K2: j8..j15
    {{128, 256, 0, 0, 0, 0, 0, 0},    2, 16, 256, 0},  // K3: j16,j17
    {{512, 1, 2, 4, 8, 16, 32, 64},   8, 18, 128, 0},  // K4: j18..j25
    {{128, 256, 0, 0, 0, 0, 0, 0},    2, 26, 256, 0},  // K5: j26,j27
};

template<int KI>
__global__ __launch_bounds__((TOUT + CFGS[KI].H) * 2)
void fused_t(const short* __restrict__ src, const float* __restrict__ x,
             const float* __restrict__ W0, const float* __restrict__ b0,
             short* __restrict__ dst, const short* __restrict__ pk,
             const float* __restrict__ bfA, const float* __restrict__ bgA,
             const float* __restrict__ brA)
{
    constexpr SegCfg cfg = CFGS[KI];
    constexpr int H = cfg.H;
    constexpr int Wp = TOUT + H;
    constexpr bool MULTI = (cfg.nl > 1);
    constexpr int LDSSZ = MULTI ? 2 * Wp * LSTR : 8;
    __shared__ short lds[LDSSZ];
    short* ldsA = lds;
    short* ldsB = lds + (MULTI ? Wp * LSTR : 0);

    const int t = threadIdx.x, lane = t & 63, wv = t >> 6;
    const int h = lane >> 4, i16 = lane & 15;
    const int tap = h >> 1, c0 = (h & 1) * 8;
    const int pbase = blockIdx.x * TOUT;
    const int bb = pbase >> 14, n0 = pbase & (NN - 1);
    const float* xrow = x + (size_t)bb * NN;
    const short* srow = src + (size_t)bb * NN * NC;

    const int l0r = wv * 32 + i16;     // this wave's tile-0 row in LDS coords
    const int l1r = l0r + 16;          // tile-1 row
    const int nA = n0 - H + l0r;       // sequence positions
    const int nB = nA + 16;

    f32x4 res0, res1;                  // fp32 residual, lives in VGPRs

    // ---- phase 0: first layer of the group, inputs from GLOBAL (no halo) ----
    {
        constexpr int d = cfg.d[0];
        constexpr int j = cfg.jbase;
        const bf16x8 af = *(const bf16x8*)(pk + OFF_WF + j * 512 + lane * 8);
        const bf16x8 ag = *(const bf16x8*)(pk + OFF_WG + j * 512 + lane * 8);
        const bf16x8 ar = *(const bf16x8*)(pk + OFF_WR + j * 512 + lane * 8);
        const f4 v1 = *(const f4*)(bfA + j * 16 + h * 4);
        const f4 v2 = *(const f4*)(bgA + j * 16 + h * 4);
        const f4 v3 = *(const f4*)(brA + j * 16 + h * 4);
        const f32x4 cf = {v1.x, v1.y, v1.z, v1.w};
        const f32x4 cg = {v2.x, v2.y, v2.z, v2.w};
        const f32x4 cr = {v3.x, v3.y, v3.z, v3.w};

        auto tile0 = [&](int l, int n, f32x4& res) {
            const int ns = tap ? n : n - d;
            bf16x8 bx = {0, 0, 0, 0, 0, 0, 0, 0};
            if (cfg.l0) {
                if (ns >= 0) {   // layer-0 output computed on the fly from x
                    const float xs = xrow[ns] * (1.0f / 32768.0f);
                    const float xm = (ns >= 1) ? xrow[ns - 1] * (1.0f / 32768.0f) : 0.0f;
#pragma unroll
                    for (int q2 = 0; q2 < 8; ++q2) {
                        const int c = c0 + q2;
                        bx[q2] = to_bf16(xs + fmaf(W0[c * 2], xm,
                                          fmaf(W0[c * 2 + 1], xs, b0[c])));
                    }
                }
            } else {
                if (ns >= 0) bx = *(const bf16x8*)(srow + (size_t)ns * NC + c0);
            }
            const f32x4 o = gated_core2(bx, af, ag, ar, cf, cg, cr);

            float r0, r1, r2, r3;        // residual input at (n, h*4..h*4+3)
            if (cfg.l0) {
                if (n >= 0) {
                    const float xs = xrow[n] * (1.0f / 32768.0f);
                    const float xm = (n >= 1) ? xrow[n - 1] * (1.0f / 32768.0f) : 0.0f;
                    const int c = h * 4;
                    r0 = xs + fmaf(W0[c * 2 + 0], xm, fmaf(W0[c * 2 + 1], xs, b0[c + 0]));
                    r1 = xs + fmaf(W0[c * 2 + 2], xm, fmaf(W0[c * 2 + 3], xs, b0[c + 1]));
                    r2 = xs + fmaf(W0[c * 2 + 4], xm, fmaf(W0[c * 2 + 5], xs, b0[c + 2]));
                    r3 = xs + fmaf(W0[c * 2 + 6], xm, fmaf(W0[c * 2 + 7], xs, b0[c + 3]));
                } else { r0 = r1 = r2 = r3 = 0.0f; }
            } else {
                if (n >= 0) {
                    const short4 ov = *(const short4*)(srow + (size_t)n * NC + h * 4);
                    r0 = from_bf16(ov.x); r1 = from_bf16(ov.y);
                    r2 = from_bf16(ov.z); r3 = from_bf16(ov.w);
                } else { r0 = r1 = r2 = r3 = 0.0f; }
            }
            res[0] = r0 + o[0]; res[1] = r1 + o[1];
            res[2] = r2 + o[2]; res[3] = r3 + o[3];
            if (MULTI) {
                *(short4*)(ldsA + l * LSTR + h * 4) =
                    make_short4(to_bf16(res[0]), to_bf16(res[1]),
                                to_bf16(res[2]), to_bf16(res[3]));
            }
        };
        tile0(l0r, nA, res0);
        tile0(l1r, nB, res1);
    }
    if (MULTI) __syncthreads();

    // ---- layers 1..nl-1: taps from LDS, residual stays in registers ----
    int cur = 0;
#pragma unroll
    for (int s = 1; s < cfg.nl; ++s) {
        const int d = cfg.d[s];
        const int j = cfg.jbase + s;
        const bf16x8 af = *(const bf16x8*)(pk + OFF_WF + j * 512 + lane * 8);
        const bf16x8 ag = *(const bf16x8*)(pk + OFF_WG + j * 512 + lane * 8);
        const bf16x8 ar = *(const bf16x8*)(pk + OFF_WR + j * 512 + lane * 8);
        const f4 v1 = *(const f4*)(bfA + j * 16 + h * 4);
        const f4 v2 = *(const f4*)(bgA + j * 16 + h * 4);
        const f4 v3 = *(const f4*)(brA + j * 16 + h * 4);
        const f32x4 cf = {v1.x, v1.y, v1.z, v1.w};
        const f32x4 cg = {v2.x, v2.y, v2.z, v2.w};
        const f32x4 cr = {v3.x, v3.y, v3.z, v3.w};
        const short* rb = cur ? ldsB : ldsA;
        short* wb = cur ? ldsA : ldsB;
        const bool wr = (s + 1 < cfg.nl);   // last layer: LDS write is dead

        auto tileL = [&](int l, int n, f32x4& res) {
            const int nt = tap ? n : n - d;
            int lt = tap ? l : l - d;
            if (lt < 0) lt = 0;          // garbage-region clamp (never read clean)
            bf16x8 bx = {0, 0, 0, 0, 0, 0, 0, 0};
            if (nt >= 0) bx = *(const bf16x8*)(rb + lt * LSTR + c0);
            const f32x4 o = gated_core2(bx, af, ag, ar, cf, cg, cr);
            res[0] += o[0]; res[1] += o[1]; res[2] += o[2]; res[3] += o[3];
            if (wr) {
                *(short4*)(wb + l * LSTR + h * 4) =
                    make_short4(to_bf16(res[0]), to_bf16(res[1]),
                                to_bf16(res[2]), to_bf16(res[3]));
            }
        };
        tileL(l0r, nA, res0);
        tileL(l1r, nB, res1);
        if (s + 1 < cfg.nl) __syncthreads();
        cur ^= 1;
    }

    // ---- writeback of owned positions from registers ----
    if (l0r >= H) {
        *(short4*)(dst + ((size_t)bb * NN + nA) * NC + h * 4) =
            make_short4(to_bf16(res0[0]), to_bf16(res0[1]),
                        to_bf16(res0[2]), to_bf16(res0[3]));
    }
    if (l1r >= H) {
        *(short4*)(dst + ((size_t)bb * NN + nB) * NC + h * 4) =
            make_short4(to_bf16(res1[0]), to_bf16(res1[1]),
                        to_bf16(res1[2]), to_bf16(res1[3]));
    }
}

// ---------------- head: fused final gated layer (j28) + 16->64->256 + LSE -----
// The last gated layer's taps come from GLOBAL (d=512, phase-0 style), its
// output crosses from 4-ch/lane to 8-ch/lane via a 512B per-wave LDS scratch,
// then the R12-proven head path (static lg indexing, direct 64B-line stores).
__global__ __launch_bounds__(512, 2) void headm_k(
    const short* __restrict__ src, const float* __restrict__ x,
    const int* __restrict__ lengths, const short* __restrict__ pk,
    const float* __restrict__ bfL, const float* __restrict__ bgL,
    const float* __restrict__ brL,
    const short* __restrict__ pka, const float* __restrict__ ba,
    const short* __restrict__ pko, const float* __restrict__ bo,
    float* __restrict__ out)
{
    __shared__ short ldsW[16384];            // all Wo fragments, 32 KB
    __shared__ short ldsS[8][256];           // per-wave [16 pos][16 ch] scratch

    const int t = threadIdx.x;
    const int lane = t & 63;
    const int wv = t >> 6;
    const int i16 = lane & 15;
    const int h = lane >> 4;
    const int pos = blockIdx.x * 128 + wv * 16 + i16;
    const int b = pos >> 14;
    const int n = pos & (NN - 1);

    // cooperative stage of Wo frags: 512 threads x 4 x 16B coalesced
#pragma unroll
    for (int i = 0; i < 4; ++i)
        ((f4*)ldsW)[t + i * 512] = ((const f4*)pko)[t + i * 512];

    // ---- fused gated layer j28 (d=512): taps from global src ----
    {
        constexpr int j = NLAY - 1;
        constexpr int d = 512;
        const short* srow = src + (size_t)b * NN * NC;
        const int tap = h >> 1, c0 = (h & 1) * 8;
        const int ns = tap ? n : n - d;
        bf16x8 bx = {0, 0, 0, 0, 0, 0, 0, 0};
        if (ns >= 0) bx = *(const bf16x8*)(srow + (size_t)ns * NC + c0);

        const bf16x8 af = *(const bf16x8*)(pk + OFF_WF + j * 512 + lane * 8);
        const bf16x8 ag = *(const bf16x8*)(pk + OFF_WG + j * 512 + lane * 8);
        const bf16x8 ar = *(const bf16x8*)(pk + OFF_WR + j * 512 + lane * 8);
        const f4 v1 = *(const f4*)(bfL + j * 16 + h * 4);
        const f4 v2 = *(const f4*)(bgL + j * 16 + h * 4);
        const f4 v3 = *(const f4*)(brL + j * 16 + h * 4);
        const f32x4 cf = {v1.x, v1.y, v1.z, v1.w};
        const f32x4 cg = {v2.x, v2.y, v2.z, v2.w};
        const f32x4 cr = {v3.x, v3.y, v3.z, v3.w};
        const f32x4 o = gated_core2(bx, af, ag, ar, cf, cg, cr);

        const short4 ov = *(const short4*)(srow + (size_t)n * NC + h * 4);
        const float xs = x[pos] * (1.0f / 32768.0f);
        // sk = relu(fin - xs), fin = residual + layer output (kept fp32 here)
        const short4 w = make_short4(
            to_bf16(fmaxf(from_bf16(ov.x) + o[0] - xs, 0.0f)),
            to_bf16(fmaxf(from_bf16(ov.y) + o[1] - xs, 0.0f)),
            to_bf16(fmaxf(from_bf16(ov.z) + o[2] - xs, 0.0f)),
            to_bf16(fmaxf(from_bf16(ov.w) + o[3] - xs, 0.0f)));
        *(short4*)(&ldsS[wv][i16 * 16 + h * 4]) = w;
    }
    __syncthreads();   // Wo frags staged + scratch visible

    // B fragment for Wa: sk channels k=h*8+j (real for h<2) from scratch
    bf16x8 bs;
    if (h < 2) {
        bs = *(const bf16x8*)(&ldsS[wv][i16 * 16 + h * 8]);
    } else {
#pragma unroll
        for (int j = 0; j < 8; ++j) bs[j] = 0;
    }

    // Wa GEMM: ra = relu(...), 16 values/lane, lane-local for Wo B-frags
    float ra[16];
#pragma unroll
    for (int mt = 0; mt < 4; ++mt) {
        const bf16x8 aa = *(const bf16x8*)(pka + (mt * 64 + lane) * 8);
        const f4 bav = *(const f4*)(ba + mt * 16 + h * 4);
        f32x4 c = {bav.x, bav.y, bav.z, bav.w};
        c = __builtin_amdgcn_mfma_f32_16x16x32_bf16(aa, bs, c, 0, 0, 0);
#pragma unroll
        for (int r = 0; r < 4; ++r) ra[mt * 4 + r] = fmaxf(c[r], 0.0f);
    }
    bf16x8 blo, bhi;
#pragma unroll
    for (int j = 0; j < 8; ++j) { blo[j] = to_bf16(ra[j]); bhi[j] = to_bf16(ra[8 + j]); }

    // Wo GEMM: 16 q-tiles x (2 MFMA, K=64); A-frags from LDS; logits in VGPRs
    float lg[64];
#pragma unroll
    for (int qt = 0; qt < 16; ++qt) {
        const bf16x8 a0 = *(const bf16x8*)(ldsW + ((qt * 2 + 0) * 64 + lane) * 8);
        const bf16x8 a1 = *(const bf16x8*)(ldsW + ((qt * 2 + 1) * 64 + lane) * 8);
        const f4 bov = *(const f4*)(bo + qt * 16 + h * 4);
        f32x4 c = {bov.x, bov.y, bov.z, bov.w};
        c = __builtin_amdgcn_mfma_f32_16x16x32_bf16(a0, blo, c, 0, 0, 0);
        c = __builtin_amdgcn_mfma_f32_16x16x32_bf16(a1, bhi, c, 0, 0, 0);
#pragma unroll
        for (int r = 0; r < 4; ++r) lg[qt * 4 + r] = c[r];
    }

    // LSE across lanes {i, i+16, i+32, i+48}
    float m = lg[0];
#pragma unroll
    for (int j = 1; j < 64; ++j) m = fmaxf(m, lg[j]);
    m = fmaxf(m, __shfl_xor(m, 16, 64));
    m = fmaxf(m, __shfl_xor(m, 32, 64));
    float s = 0.0f;
#pragma unroll
    for (int j = 0; j < 64; ++j) s += __expf(lg[j] - m);
    s += __shfl_xor(s, 16, 64);
    s += __shfl_xor(s, 32, 64);
    const float lse = m + __logf(s);
    const bool valid = n < lengths[b];

    // write: q = qt*16 + h*4 + r at out[b][q][n] (full 64B lines per h-group)
    float* ob = out + (size_t)b * 256 * NN + n;
#pragma unroll
    for (int qt = 0; qt < 16; ++qt)
#pragma unroll
        for (int r = 0; r < 4; ++r)
            ob[(size_t)(qt * 16 + h * 4 + r) * NN] = valid ? (lg[qt * 4 + r] - lse) : 0.0f;
}

extern "C" void kernel_launch(void* const* d_in, const int* in_sizes, int n_in,
                              void* d_out, int out_size, void* d_ws, size_t ws_size,
                              hipStream_t stream)
{
    const float* x       = (const float*)d_in[0];
    const int*   lengths = (const int*)d_in[1];
    const float* W0      = (const float*)d_in[2];
    const float* b0      = (const float*)d_in[3];
    const float* Wf      = (const float*)d_in[4];
    const float* bf      = (const float*)d_in[5];
    const float* Wg      = (const float*)d_in[6];
    const float* bg      = (const float*)d_in[7];
    const float* Wr      = (const float*)d_in[8];
    const float* br      = (const float*)d_in[9];
    const float* Wa      = (const float*)d_in[10];
    const float* ba      = (const float*)d_in[11];
    const float* Wo      = (const float*)d_in[12];
    const float* bo      = (const float*)d_in[13];
    float* out = (float*)d_out;

    short* bufA = (short*)d_ws;                         // (B,N,16) bf16, 4.2 MB
    short* bufB = bufA + (size_t)NPOSTOT * NC;
    short* pk   = bufB + (size_t)NPOSTOT * NC;          // packed weight frags

    prepack_k<<<dim3((PK_TOT + 255) / 256), dim3(256), 0, stream>>>(
        Wf, Wg, Wr, Wa, Wo, pk);

#define FUSED(K, SRC, DST)                                                     \
    fused_t<K><<<dim3(NPOSTOT / TOUT), dim3((TOUT + CFGS[K].H) * 2), 0,        \
                 stream>>>(SRC, x, W0, b0, DST, pk, bf, bg, br)

    FUSED(0, bufA, bufA);   // src unused (l0 mode)
    FUSED(1, bufA, bufB);
    FUSED(2, bufB, bufA);
    FUSED(3, bufA, bufB);
    FUSED(4, bufB, bufA);
    FUSED(5, bufA, bufB);
#undef FUSED

    // head consumes K5's output (bufB) and fuses gated layer j28 inline
    headm_k<<<dim3(NPOSTOT / 128), dim3(512), 0, stream>>>(
        bufB, x, lengths, pk, bf, bg, br,
        pk + OFF_WA, ba, pk + OFF_WO, bo, out);
}

// Round 20
// 132.445 us; speedup vs baseline: 1.1415x; 1.0282x over previous
//
#include <hip/hip_runtime.h>
#include <hip/hip_bf16.h>

#define NN 16384          // sequence length
#define NC 16             // layer channels
#define NPOSTOT 131072    // 8 * 16384
#define NLAY 29           // gated layers
#define TOUT 256          // output positions per block
#define LSTR 24           // LDS row stride in shorts (48 B -> bank-uniform)

typedef float4 f4;
typedef short bf16x8 __attribute__((ext_vector_type(8)));
typedef float f32x4 __attribute__((ext_vector_type(4)));

// prepack element offsets (in shorts)
#define OFF_WF 0
#define OFF_WG (NLAY * 512)
#define OFF_WR (2 * NLAY * 512)
#define OFF_WA (3 * NLAY * 512)
#define OFF_WO (3 * NLAY * 512 + 2048)
#define PK_TOT (OFF_WO + 16384)

static __device__ __forceinline__ short to_bf16(float f) {
    __hip_bfloat16 h = __float2bfloat16(f);   // RNE
    short s;
    __builtin_memcpy(&s, &h, 2);
    return s;
}
static __device__ __forceinline__ float from_bf16(short s) {
    unsigned int u = ((unsigned int)(unsigned short)s) << 16;
    float f;
    __builtin_memcpy(&f, &u, 4);
    return f;
}

// ---------------- weight prepack into MFMA A-fragments (bf16) -----------------
// Slot-consistency: A and B packed with the same (h=lane>>4, j)->k bijection.
//  conv (K=32):  k = h*8+j ; tap = k>>4, c = k&15           (B from memory)
//  1x1  (K=32):  j<4 -> k = h*4+j (=channel), j>=4 -> zero  (B = conv output)
//  Wa   (K=32):  k = h*8+j, real for k<16 (c=k), else zero  (B from memory)
//  Wo   (K=64):  half hf, k = hf*32 + (j>>2)*16 + h*4 + (j&3)  (B = Wa output)
__global__ __launch_bounds__(256) void prepack_k(
    const float* __restrict__ Wf, const float* __restrict__ Wg,
    const float* __restrict__ Wr, const float* __restrict__ Wa,
    const float* __restrict__ Wo, short* __restrict__ pk)
{
    const int i = blockIdx.x * 256 + threadIdx.x;
    if (i >= PK_TOT) return;
    float val;
    if (i < OFF_WG) {                               // Wf frags
        const int j = i >> 9, r = i & 511, l = r >> 3, j8 = r & 7;
        const int o = l & 15, h = l >> 4;
        const int k = h * 8 + j8, tap = k >> 4, c = k & 15;
        val = Wf[((j * 16 + o) * 16 + c) * 2 + tap];
    } else if (i < OFF_WA) {
        const int i2 = i - OFF_WG;
        if (i2 < NLAY * 512) {                      // Wg frags
            const int j = i2 >> 9, r = i2 & 511, l = r >> 3, j8 = r & 7;
            const int o = l & 15, h = l >> 4;
            const int k = h * 8 + j8, tap = k >> 4, c = k & 15;
            val = Wg[((j * 16 + o) * 16 + c) * 2 + tap];
        } else {                                    // Wr frags (half zero-padded)
            const int i3 = i2 - NLAY * 512;
            const int j = i3 >> 9, r = i3 & 511, l = r >> 3, j8 = r & 7;
            const int o = l & 15, h = l >> 4;
            val = (j8 < 4) ? Wr[j * 256 + o * 16 + h * 4 + j8] : 0.0f;
        }
    } else if (i < OFF_WO) {                        // Wa frags (4 m-tiles)
        const int i2 = i - OFF_WA;
        const int mt = i2 >> 9, r = i2 & 511, l = r >> 3, j8 = r & 7;
        const int og = mt * 16 + (l & 15), h = l >> 4;
        const int k = h * 8 + j8;
        val = (k < 16) ? Wa[og * 16 + k] : 0.0f;
    } else {                                        // Wo frags (16 q-tiles x 2 halves)
        const int i2 = i - OFF_WO;
        const int qt = i2 >> 10, hf = (i2 >> 9) & 1, r = i2 & 511;
        const int l = r >> 3, j8 = r & 7;
        const int q = qt * 16 + (l & 15), h = l >> 4;
        const int kg = hf * 32 + (j8 >> 2) * 16 + h * 4 + (j8 & 3);
        val = Wo[q * 64 + kg];
    }
    pk[i] = to_bf16(val);
}

// ---------------- gated MFMA core: 2 conv MFMA + merged act + 1x1 MFMA -------
static __device__ __forceinline__ f32x4 gated_core2(
    bf16x8 bx, bf16x8 af_, bf16x8 ag_, bf16x8 ar_,
    f32x4 cf, f32x4 cg, f32x4 cr)
{
    const f32x4 fp = __builtin_amdgcn_mfma_f32_16x16x32_bf16(af_, bx, cf, 0, 0, 0);
    const f32x4 gp = __builtin_amdgcn_mfma_f32_16x16x32_bf16(ag_, bx, cg, 0, 0, 0);

    bf16x8 bz;
#pragma unroll
    for (int r = 0; r < 4; ++r) {
        // z = tanh(f)*sigmoid(g) = (e^{2f}-1) / ((e^{2f}+1)(1+e^{-g}))
        const float ef = __expf(2.0f * fminf(fp[r], 43.0f));   // clamp: no inf
        const float eg = __expf(-gp[r]);
        const float den = fmaf(ef, eg, ef) + (eg + 1.0f);
        bz[r] = to_bf16((ef - 1.0f) * __builtin_amdgcn_rcpf(den));
        bz[r + 4] = 0;
    }
    return __builtin_amdgcn_mfma_f32_16x16x32_bf16(ar_, bz, cr, 0, 0, 0);
}

// ---------------- fused multi-layer segment kernel (R17 template) -------------
// 6-dispatch schedule; j27 and j28 moved into the head (K5 is now a single).
struct SegCfg { int d[8]; int nl; int jbase; int H; int l0; };

constexpr SegCfg CFGS[6] = {
    {{2, 4, 8, 16, 32, 64, 0, 0},     6, 0,  128, 1},  // K0: L0 + j0..j5
    {{128, 256, 0, 0, 0, 0, 0, 0},    2, 6,  256, 0},  // K1: j6,j7
    {{512, 1, 2, 4, 8, 16, 32, 64},   8, 8,  128, 0},  // K2: j8..j15
    {{128, 256, 0, 0, 0, 0, 0, 0},    2, 16, 256, 0},  // K3: j16,j17
    {{512, 1, 2, 4, 8, 16, 32, 64},   8, 18, 128, 0},  // K4: j18..j25
    {{128, 0, 0, 0, 0, 0, 0, 0},      1, 26, 0,   0},  // K5: j26 (single)
};

template<int KI>
__global__ __launch_bounds__((TOUT + CFGS[KI].H) * 2)
void fused_t(const short* __restrict__ src, const float* __restrict__ x,
             const float* __restrict__ W0, const float* __restrict__ b0,
             short* __restrict__ dst, const short* __restrict__ pk,
             const float* __restrict__ bfA, const float* __restrict__ bgA,
             const float* __restrict__ brA)
{
    constexpr SegCfg cfg = CFGS[KI];
    constexpr int H = cfg.H;
    constexpr int Wp = TOUT + H;
    constexpr bool MULTI = (cfg.nl > 1);
    constexpr int LDSSZ = MULTI ? 2 * Wp * LSTR : 8;
    __shared__ short lds[LDSSZ];
    short* ldsA = lds;
    short* ldsB = lds + (MULTI ? Wp * LSTR : 0);

    const int t = threadIdx.x, lane = t & 63, wv = t >> 6;
    const int h = lane >> 4, i16 = lane & 15;
    const int tap = h >> 1, c0 = (h & 1) * 8;
    const int pbase = blockIdx.x * TOUT;
    const int bb = pbase >> 14, n0 = pbase & (NN - 1);
    const float* xrow = x + (size_t)bb * NN;
    const short* srow = src + (size_t)bb * NN * NC;

    const int l0r = wv * 32 + i16;     // this wave's tile-0 row in LDS coords
    const int l1r = l0r + 16;          // tile-1 row
    const int nA = n0 - H + l0r;       // sequence positions
    const int nB = nA + 16;

    f32x4 res0, res1;                  // fp32 residual, lives in VGPRs

    // ---- phase 0: first layer of the group, inputs from GLOBAL (no halo) ----
    {
        constexpr int d = cfg.d[0];
        constexpr int j = cfg.jbase;
        const bf16x8 af = *(const bf16x8*)(pk + OFF_WF + j * 512 + lane * 8);
        const bf16x8 ag = *(const bf16x8*)(pk + OFF_WG + j * 512 + lane * 8);
        const bf16x8 ar = *(const bf16x8*)(pk + OFF_WR + j * 512 + lane * 8);
        const f4 v1 = *(const f4*)(bfA + j * 16 + h * 4);
        const f4 v2 = *(const f4*)(bgA + j * 16 + h * 4);
        const f4 v3 = *(const f4*)(brA + j * 16 + h * 4);
        const f32x4 cf = {v1.x, v1.y, v1.z, v1.w};
        const f32x4 cg = {v2.x, v2.y, v2.z, v2.w};
        const f32x4 cr = {v3.x, v3.y, v3.z, v3.w};

        auto tile0 = [&](int l, int n, f32x4& res) {
            const int ns = tap ? n : n - d;
            bf16x8 bx = {0, 0, 0, 0, 0, 0, 0, 0};
            if (cfg.l0) {
                if (ns >= 0) {   // layer-0 output computed on the fly from x
                    const float xs = xrow[ns] * (1.0f / 32768.0f);
                    const float xm = (ns >= 1) ? xrow[ns - 1] * (1.0f / 32768.0f) : 0.0f;
#pragma unroll
                    for (int q2 = 0; q2 < 8; ++q2) {
                        const int c = c0 + q2;
                        bx[q2] = to_bf16(xs + fmaf(W0[c * 2], xm,
                                          fmaf(W0[c * 2 + 1], xs, b0[c])));
                    }
                }
            } else {
                if (ns >= 0) bx = *(const bf16x8*)(srow + (size_t)ns * NC + c0);
            }
            const f32x4 o = gated_core2(bx, af, ag, ar, cf, cg, cr);

            float r0, r1, r2, r3;        // residual input at (n, h*4..h*4+3)
            if (cfg.l0) {
                if (n >= 0) {
                    const float xs = xrow[n] * (1.0f / 32768.0f);
                    const float xm = (n >= 1) ? xrow[n - 1] * (1.0f / 32768.0f) : 0.0f;
                    const int c = h * 4;
                    r0 = xs + fmaf(W0[c * 2 + 0], xm, fmaf(W0[c * 2 + 1], xs, b0[c + 0]));
                    r1 = xs + fmaf(W0[c * 2 + 2], xm, fmaf(W0[c * 2 + 3], xs, b0[c + 1]));
                    r2 = xs + fmaf(W0[c * 2 + 4], xm, fmaf(W0[c * 2 + 5], xs, b0[c + 2]));
                    r3 = xs + fmaf(W0[c * 2 + 6], xm, fmaf(W0[c * 2 + 7], xs, b0[c + 3]));
                } else { r0 = r1 = r2 = r3 = 0.0f; }
            } else {
                if (n >= 0) {
                    const short4 ov = *(const short4*)(srow + (size_t)n * NC + h * 4);
                    r0 = from_bf16(ov.x); r1 = from_bf16(ov.y);
                    r2 = from_bf16(ov.z); r3 = from_bf16(ov.w);
                } else { r0 = r1 = r2 = r3 = 0.0f; }
            }
            res[0] = r0 + o[0]; res[1] = r1 + o[1];
            res[2] = r2 + o[2]; res[3] = r3 + o[3];
            if (MULTI) {
                *(short4*)(ldsA + l * LSTR + h * 4) =
                    make_short4(to_bf16(res[0]), to_bf16(res[1]),
                                to_bf16(res[2]), to_bf16(res[3]));
            }
        };
        tile0(l0r, nA, res0);
        tile0(l1r, nB, res1);
    }
    if (MULTI) __syncthreads();

    // ---- layers 1..nl-1: taps from LDS, residual stays in registers ----
    int cur = 0;
#pragma unroll
    for (int s = 1; s < cfg.nl; ++s) {
        const int d = cfg.d[s];
        const int j = cfg.jbase + s;
        const bf16x8 af = *(const bf16x8*)(pk + OFF_WF + j * 512 + lane * 8);
        const bf16x8 ag = *(const bf16x8*)(pk + OFF_WG + j * 512 + lane * 8);
        const bf16x8 ar = *(const bf16x8*)(pk + OFF_WR + j * 512 + lane * 8);
        const f4 v1 = *(const f4*)(bfA + j * 16 + h * 4);
        const f4 v2 = *(const f4*)(bgA + j * 16 + h * 4);
        const f4 v3 = *(const f4*)(brA + j * 16 + h * 4);
        const f32x4 cf = {v1.x, v1.y, v1.z, v1.w};
        const f32x4 cg = {v2.x, v2.y, v2.z, v2.w};
        const f32x4 cr = {v3.x, v3.y, v3.z, v3.w};
        const short* rb = cur ? ldsB : ldsA;
        short* wb = cur ? ldsA : ldsB;
        const bool wr = (s + 1 < cfg.nl);   // last layer: LDS write is dead

        auto tileL = [&](int l, int n, f32x4& res) {
            const int nt = tap ? n : n - d;
            int lt = tap ? l : l - d;
            if (lt < 0) lt = 0;          // garbage-region clamp (never read clean)
            bf16x8 bx = {0, 0, 0, 0, 0, 0, 0, 0};
            if (nt >= 0) bx = *(const bf16x8*)(rb + lt * LSTR + c0);
            const f32x4 o = gated_core2(bx, af, ag, ar, cf, cg, cr);
            res[0] += o[0]; res[1] += o[1]; res[2] += o[2]; res[3] += o[3];
            if (wr) {
                *(short4*)(wb + l * LSTR + h * 4) =
                    make_short4(to_bf16(res[0]), to_bf16(res[1]),
                                to_bf16(res[2]), to_bf16(res[3]));
            }
        };
        tileL(l0r, nA, res0);
        tileL(l1r, nB, res1);
        if (s + 1 < cfg.nl) __syncthreads();
        cur ^= 1;
    }

    // ---- writeback of owned positions from registers ----
    if (l0r >= H) {
        *(short4*)(dst + ((size_t)bb * NN + nA) * NC + h * 4) =
            make_short4(to_bf16(res0[0]), to_bf16(res0[1]),
                        to_bf16(res0[2]), to_bf16(res0[3]));
    }
    if (l1r >= H) {
        *(short4*)(dst + ((size_t)bb * NN + nB) * NC + h * 4) =
            make_short4(to_bf16(res1[0]), to_bf16(res1[1]),
                        to_bf16(res1[2]), to_bf16(res1[3]));
    }
}

// ---------------- head: fused j27 (d=256) + j28 (d=512) + 16->64->256 + LSE ---
// src = post-j26 stream. j27 computed at n and n-512 (the latter feeds j28's
// tap0); 4-ch/lane -> 8-ch/lane crossovers via per-wave LDS scratch (wave-
// local, no barrier: same-array LDS deps are compiler-ordered within a wave).
__global__ __launch_bounds__(512, 2) void headm_k(
    const short* __restrict__ src, const float* __restrict__ x,
    const int* __restrict__ lengths, const short* __restrict__ pk,
    const float* __restrict__ bfL, const float* __restrict__ bgL,
    const float* __restrict__ brL,
    const short* __restrict__ pka, const float* __restrict__ ba,
    const short* __restrict__ pko, const float* __restrict__ bo,
    float* __restrict__ out)
{
    __shared__ short ldsW[16384];            // all Wo fragments, 32 KB
    __shared__ short ldsS0[8][256];          // post-j27 at n      (per-wave)
    __shared__ short ldsS1[8][256];          // post-j27 at n-512  (per-wave)
    __shared__ short ldsS2[8][256];          // sk                 (per-wave)

    const int t = threadIdx.x;
    const int lane = t & 63;
    const int wv = t >> 6;
    const int i16 = lane & 15;
    const int h = lane >> 4;
    const int pos = blockIdx.x * 128 + wv * 16 + i16;
    const int b = pos >> 14;
    const int n = pos & (NN - 1);
    const int tap = h >> 1, c0 = (h & 1) * 8;
    const short* srow = src + (size_t)b * NN * NC;

    // cooperative stage of Wo frags: 512 threads x 4 x 16B coalesced
#pragma unroll
    for (int i = 0; i < 4; ++i)
        ((f4*)ldsW)[t + i * 512] = ((const f4*)pko)[t + i * 512];

    // ---- fused gated layer j27 (d=256) at n and n-512 ----
    f32x4 r27n;
    {
        constexpr int j = NLAY - 2;          // 27
        const bf16x8 af = *(const bf16x8*)(pk + OFF_WF + j * 512 + lane * 8);
        const bf16x8 ag = *(const bf16x8*)(pk + OFF_WG + j * 512 + lane * 8);
        const bf16x8 ar = *(const bf16x8*)(pk + OFF_WR + j * 512 + lane * 8);
        const f4 v1 = *(const f4*)(bfL + j * 16 + h * 4);
        const f4 v2 = *(const f4*)(bgL + j * 16 + h * 4);
        const f4 v3 = *(const f4*)(brL + j * 16 + h * 4);
        const f32x4 cf = {v1.x, v1.y, v1.z, v1.w};
        const f32x4 cg = {v2.x, v2.y, v2.z, v2.w};
        const f32x4 cr = {v3.x, v3.y, v3.z, v3.w};

        auto run27 = [&](int p, short* dstS) -> f32x4 {
            const int ns = tap ? p : p - 256;
            bf16x8 bx = {0, 0, 0, 0, 0, 0, 0, 0};
            if (ns >= 0) bx = *(const bf16x8*)(srow + (size_t)ns * NC + c0);
            const f32x4 o = gated_core2(bx, af, ag, ar, cf, cg, cr);
            const short4 ov = *(const short4*)(srow + (size_t)p * NC + h * 4);
            f32x4 r;
            r[0] = from_bf16(ov.x) + o[0]; r[1] = from_bf16(ov.y) + o[1];
            r[2] = from_bf16(ov.z) + o[2]; r[3] = from_bf16(ov.w) + o[3];
            *(short4*)(dstS + i16 * 16 + h * 4) =
                make_short4(to_bf16(r[0]), to_bf16(r[1]),
                            to_bf16(r[2]), to_bf16(r[3]));
            return r;
        };
        r27n = run27(n, &ldsS0[wv][0]);
        if (n >= 512) run27(n - 512, &ldsS1[wv][0]);
    }

    // ---- fused gated layer j28 (d=512): taps from the wave-local scratch ----
    {
        constexpr int j = NLAY - 1;          // 28
        const bf16x8 af = *(const bf16x8*)(pk + OFF_WF + j * 512 + lane * 8);
        const bf16x8 ag = *(const bf16x8*)(pk + OFF_WG + j * 512 + lane * 8);
        const bf16x8 ar = *(const bf16x8*)(pk + OFF_WR + j * 512 + lane * 8);
        const f4 v1 = *(const f4*)(bfL + j * 16 + h * 4);
        const f4 v2 = *(const f4*)(bgL + j * 16 + h * 4);
        const f4 v3 = *(const f4*)(brL + j * 16 + h * 4);
        const f32x4 cf = {v1.x, v1.y, v1.z, v1.w};
        const f32x4 cg = {v2.x, v2.y, v2.z, v2.w};
        const f32x4 cr = {v3.x, v3.y, v3.z, v3.w};

        bf16x8 bx = {0, 0, 0, 0, 0, 0, 0, 0};
        if (tap) {
            bx = *(const bf16x8*)(&ldsS0[wv][i16 * 16 + c0]);
        } else if (n >= 512) {
            bx = *(const bf16x8*)(&ldsS1[wv][i16 * 16 + c0]);
        }
        const f32x4 o = gated_core2(bx, af, ag, ar, cf, cg, cr);

        const float xs = x[pos] * (1.0f / 32768.0f);
        // sk = relu(fin - xs), fin = r27n + o (kept fp32)
        *(short4*)(&ldsS2[wv][i16 * 16 + h * 4]) = make_short4(
            to_bf16(fmaxf(r27n[0] + o[0] - xs, 0.0f)),
            to_bf16(fmaxf(r27n[1] + o[1] - xs, 0.0f)),
            to_bf16(fmaxf(r27n[2] + o[2] - xs, 0.0f)),
            to_bf16(fmaxf(r27n[3] + o[3] - xs, 0.0f)));
    }

    // B fragment for Wa: sk channels k=h*8+j (real for h<2) from scratch
    bf16x8 bs;
    if (h < 2) {
        bs = *(const bf16x8*)(&ldsS2[wv][i16 * 16 + h * 8]);
    } else {
#pragma unroll
        for (int j = 0; j < 8; ++j) bs[j] = 0;
    }

    // Wa GEMM: ra = relu(...), 16 values/lane, lane-local for Wo B-frags
    float ra[16];
#pragma unroll
    for (int mt = 0; mt < 4; ++mt) {
        const bf16x8 aa = *(const bf16x8*)(pka + (mt * 64 + lane) * 8);
        const f4 bav = *(const f4*)(ba + mt * 16 + h * 4);
        f32x4 c = {bav.x, bav.y, bav.z, bav.w};
        c = __builtin_amdgcn_mfma_f32_16x16x32_bf16(aa, bs, c, 0, 0, 0);
#pragma unroll
        for (int r = 0; r < 4; ++r) ra[mt * 4 + r] = fmaxf(c[r], 0.0f);
    }
    bf16x8 blo, bhi;
#pragma unroll
    for (int j = 0; j < 8; ++j) { blo[j] = to_bf16(ra[j]); bhi[j] = to_bf16(ra[8 + j]); }

    __syncthreads();   // Wo frags staged (ldsW)

    // Wo GEMM: 16 q-tiles x (2 MFMA, K=64); A-frags from LDS; logits in VGPRs
    float lg[64];
#pragma unroll
    for (int qt = 0; qt < 16; ++qt) {
        const bf16x8 a0 = *(const bf16x8*)(ldsW + ((qt * 2 + 0) * 64 + lane) * 8);
        const bf16x8 a1 = *(const bf16x8*)(ldsW + ((qt * 2 + 1) * 64 + lane) * 8);
        const f4 bov = *(const f4*)(bo + qt * 16 + h * 4);
        f32x4 c = {bov.x, bov.y, bov.z, bov.w};
        c = __builtin_amdgcn_mfma_f32_16x16x32_bf16(a0, blo, c, 0, 0, 0);
        c = __builtin_amdgcn_mfma_f32_16x16x32_bf16(a1, bhi, c, 0, 0, 0);
#pragma unroll
        for (int r = 0; r < 4; ++r) lg[qt * 4 + r] = c[r];
    }

    // LSE across lanes {i, i+16, i+32, i+48}
    float m = lg[0];
#pragma unroll
    for (int j = 1; j < 64; ++j) m = fmaxf(m, lg[j]);
    m = fmaxf(m, __shfl_xor(m, 16, 64));
    m = fmaxf(m, __shfl_xor(m, 32, 64));
    float s = 0.0f;
#pragma unroll
    for (int j = 0; j < 64; ++j) s += __expf(lg[j] - m);
    s += __shfl_xor(s, 16, 64);
    s += __shfl_xor(s, 32, 64);
    const float lse = m + __logf(s);
    const bool valid = n < lengths[b];

    // write: q = qt*16 + h*4 + r at out[b][q][n] (full 64B lines per h-group)
    float* ob = out + (size_t)b * 256 * NN + n;
#pragma unroll
    for (int qt = 0; qt < 16; ++qt)
#pragma unroll
        for (int r = 0; r < 4; ++r)
            ob[(size_t)(qt * 16 + h * 4 + r) * NN] = valid ? (lg[qt * 4 + r] - lse) : 0.0f;
}

extern "C" void kernel_launch(void* const* d_in, const int* in_sizes, int n_in,
                              void* d_out, int out_size, void* d_ws, size_t ws_size,
                              hipStream_t stream)
{
    const float* x       = (const float*)d_in[0];
    const int*   lengths = (const int*)d_in[1];
    const float* W0      = (const float*)d_in[2];
    const float* b0      = (const float*)d_in[3];
    const float* Wf      = (const float*)d_in[4];
    const float* bf      = (const float*)d_in[5];
    const float* Wg      = (const float*)d_in[6];
    const float* bg      = (const float*)d_in[7];
    const float* Wr      = (const float*)d_in[8];
    const float* br      = (const float*)d_in[9];
    const float* Wa      = (const float*)d_in[10];
    const float* ba      = (const float*)d_in[11];
    const float* Wo      = (const float*)d_in[12];
    const float* bo      = (const float*)d_in[13];
    float* out = (float*)d_out;

    short* bufA = (short*)d_ws;                         // (B,N,16) bf16, 4.2 MB
    short* bufB = bufA + (size_t)NPOSTOT * NC;
    short* pk   = bufB + (size_t)NPOSTOT * NC;          // packed weight frags

    prepack_k<<<dim3((PK_TOT + 255) / 256), dim3(256), 0, stream>>>(
        Wf, Wg, Wr, Wa, Wo, pk);

#define FUSED(K, SRC, DST)                                                     \
    fused_t<K><<<dim3(NPOSTOT / TOUT), dim3((TOUT + CFGS[K].H) * 2), 0,        \
                 stream>>>(SRC, x, W0, b0, DST, pk, bf, bg, br)

    FUSED(0, bufA, bufA);   // src unused (l0 mode)
    FUSED(1, bufA, bufB);
    FUSED(2, bufB, bufA);
    FUSED(3, bufA, bufB);
    FUSED(4, bufB, bufA);
    FUSED(5, bufA, bufB);   // j26 single -> bufB (post-j26)
#undef FUSED

    // head consumes post-j26 (bufB), fuses j27 + j28 inline
    headm_k<<<dim3(NPOSTOT / 128), dim3(512), 0, stream>>>(
        bufB, x, lengths, pk, bf, bg, br,
        pk + OFF_WA, ba, pk + OFF_WO, bo, out);
}

// Round 21
// 130.668 us; speedup vs baseline: 1.1570x; 1.0136x over previous
//
#include <hip/hip_runtime.h>
#include <hip/hip_bf16.h>

#define NN 16384          // sequence length
#define NC 16             // layer channels
#define NPOSTOT 131072    // 8 * 16384
#define NLAY 29           // gated layers
#define TOUT 256          // output positions per block
#define LSTR 24           // LDS row stride in shorts (48 B -> bank-uniform)

typedef float4 f4;
typedef short bf16x8 __attribute__((ext_vector_type(8)));
typedef float f32x4 __attribute__((ext_vector_type(4)));

// prepack element offsets (in shorts)
#define OFF_WF 0
#define OFF_WG (NLAY * 512)
#define OFF_WR (2 * NLAY * 512)
#define OFF_WA (3 * NLAY * 512)
#define OFF_WO (3 * NLAY * 512 + 2048)
#define PK_TOT (OFF_WO + 16384)

static __device__ __forceinline__ short to_bf16(float f) {
    __hip_bfloat16 h = __float2bfloat16(f);   // RNE
    short s;
    __builtin_memcpy(&s, &h, 2);
    return s;
}
static __device__ __forceinline__ float from_bf16(short s) {
    unsigned int u = ((unsigned int)(unsigned short)s) << 16;
    float f;
    __builtin_memcpy(&f, &u, 4);
    return f;
}

// ---------------- weight prepack into MFMA A-fragments (bf16) -----------------
// Slot-consistency: A and B packed with the same (h=lane>>4, j)->k bijection.
//  conv (K=32):  k = h*8+j ; tap = k>>4, c = k&15           (B from memory)
//  1x1  (K=32):  j<4 -> k = h*4+j (=channel), j>=4 -> zero  (B = conv output)
//  Wa   (K=32):  k = h*8+j, real for k<16 (c=k), else zero  (B from memory)
//  Wo   (K=64):  half hf, k = hf*32 + (j>>2)*16 + h*4 + (j&3)  (B = Wa output)
__global__ __launch_bounds__(256) void prepack_k(
    const float* __restrict__ Wf, const float* __restrict__ Wg,
    const float* __restrict__ Wr, const float* __restrict__ Wa,
    const float* __restrict__ Wo, short* __restrict__ pk)
{
    const int i = blockIdx.x * 256 + threadIdx.x;
    if (i >= PK_TOT) return;
    float val;
    if (i < OFF_WG) {                               // Wf frags
        const int j = i >> 9, r = i & 511, l = r >> 3, j8 = r & 7;
        const int o = l & 15, h = l >> 4;
        const int k = h * 8 + j8, tap = k >> 4, c = k & 15;
        val = Wf[((j * 16 + o) * 16 + c) * 2 + tap];
    } else if (i < OFF_WA) {
        const int i2 = i - OFF_WG;
        if (i2 < NLAY * 512) {                      // Wg frags
            const int j = i2 >> 9, r = i2 & 511, l = r >> 3, j8 = r & 7;
            const int o = l & 15, h = l >> 4;
            const int k = h * 8 + j8, tap = k >> 4, c = k & 15;
            val = Wg[((j * 16 + o) * 16 + c) * 2 + tap];
        } else {                                    // Wr frags (half zero-padded)
            const int i3 = i2 - NLAY * 512;
            const int j = i3 >> 9, r = i3 & 511, l = r >> 3, j8 = r & 7;
            const int o = l & 15, h = l >> 4;
            val = (j8 < 4) ? Wr[j * 256 + o * 16 + h * 4 + j8] : 0.0f;
        }
    } else if (i < OFF_WO) {                        // Wa frags (4 m-tiles)
        const int i2 = i - OFF_WA;
        const int mt = i2 >> 9, r = i2 & 511, l = r >> 3, j8 = r & 7;
        const int og = mt * 16 + (l & 15), h = l >> 4;
        const int k = h * 8 + j8;
        val = (k < 16) ? Wa[og * 16 + k] : 0.0f;
    } else {                                        // Wo frags (16 q-tiles x 2 halves)
        const int i2 = i - OFF_WO;
        const int qt = i2 >> 10, hf = (i2 >> 9) & 1, r = i2 & 511;
        const int l = r >> 3, j8 = r & 7;
        const int q = qt * 16 + (l & 15), h = l >> 4;
        const int kg = hf * 32 + (j8 >> 2) * 16 + h * 4 + (j8 & 3);
        val = Wo[q * 64 + kg];
    }
    pk[i] = to_bf16(val);
}

// ---------------- gated MFMA core: 2 conv MFMA + merged act + 1x1 MFMA -------
static __device__ __forceinline__ f32x4 gated_core2(
    bf16x8 bx, bf16x8 af_, bf16x8 ag_, bf16x8 ar_,
    f32x4 cf, f32x4 cg, f32x4 cr)
{
    const f32x4 fp = __builtin_amdgcn_mfma_f32_16x16x32_bf16(af_, bx, cf, 0, 0, 0);
    const f32x4 gp = __builtin_amdgcn_mfma_f32_16x16x32_bf16(ag_, bx, cg, 0, 0, 0);

    bf16x8 bz;
#pragma unroll
    for (int r = 0; r < 4; ++r) {
        // z = tanh(f)*sigmoid(g) = (e^{2f}-1) / ((e^{2f}+1)(1+e^{-g}))
        const float ef = __expf(2.0f * fminf(fp[r], 43.0f));   // clamp: no inf
        const float eg = __expf(-gp[r]);
        const float den = fmaf(ef, eg, ef) + (eg + 1.0f);
        bz[r] = to_bf16((ef - 1.0f) * __builtin_amdgcn_rcpf(den));
        bz[r + 4] = 0;
    }
    return __builtin_amdgcn_mfma_f32_16x16x32_bf16(ar_, bz, cr, 0, 0, 0);
}

// ---------------- fused multi-layer segment kernel (R17 template) -------------
// 5-dispatch schedule; j26, j27, j28 all moved into the head.
struct SegCfg { int d[8]; int nl; int jbase; int H; int l0; };

constexpr SegCfg CFGS[5] = {
    {{2, 4, 8, 16, 32, 64, 0, 0},     6, 0,  128, 1},  // K0: L0 + j0..j5
    {{128, 256, 0, 0, 0, 0, 0, 0},    2, 6,  256, 0},  // K1: j6,j7
    {{512, 1, 2, 4, 8, 16, 32, 64},   8, 8,  128, 0},  // K2: j8..j15
    {{128, 256, 0, 0, 0, 0, 0, 0},    2, 16, 256, 0},  // K3: j16,j17
    {{512, 1, 2, 4, 8, 16, 32, 64},   8, 18, 128, 0},  // K4: j18..j25
};

template<int KI>
__global__ __launch_bounds__((TOUT + CFGS[KI].H) * 2)
void fused_t(const short* __restrict__ src, const float* __restrict__ x,
             const float* __restrict__ W0, const float* __restrict__ b0,
             short* __restrict__ dst, const short* __restrict__ pk,
             const float* __restrict__ bfA, const float* __restrict__ bgA,
             const float* __restrict__ brA)
{
    constexpr SegCfg cfg = CFGS[KI];
    constexpr int H = cfg.H;
    constexpr int Wp = TOUT + H;
    constexpr bool MULTI = (cfg.nl > 1);
    constexpr int LDSSZ = MULTI ? 2 * Wp * LSTR : 8;
    __shared__ short lds[LDSSZ];
    short* ldsA = lds;
    short* ldsB = lds + (MULTI ? Wp * LSTR : 0);

    const int t = threadIdx.x, lane = t & 63, wv = t >> 6;
    const int h = lane >> 4, i16 = lane & 15;
    const int tap = h >> 1, c0 = (h & 1) * 8;
    const int pbase = blockIdx.x * TOUT;
    const int bb = pbase >> 14, n0 = pbase & (NN - 1);
    const float* xrow = x + (size_t)bb * NN;
    const short* srow = src + (size_t)bb * NN * NC;

    const int l0r = wv * 32 + i16;     // this wave's tile-0 row in LDS coords
    const int l1r = l0r + 16;          // tile-1 row
    const int nA = n0 - H + l0r;       // sequence positions
    const int nB = nA + 16;

    f32x4 res0, res1;                  // fp32 residual, lives in VGPRs

    // ---- phase 0: first layer of the group, inputs from GLOBAL (no halo) ----
    {
        constexpr int d = cfg.d[0];
        constexpr int j = cfg.jbase;
        const bf16x8 af = *(const bf16x8*)(pk + OFF_WF + j * 512 + lane * 8);
        const bf16x8 ag = *(const bf16x8*)(pk + OFF_WG + j * 512 + lane * 8);
        const bf16x8 ar = *(const bf16x8*)(pk + OFF_WR + j * 512 + lane * 8);
        const f4 v1 = *(const f4*)(bfA + j * 16 + h * 4);
        const f4 v2 = *(const f4*)(bgA + j * 16 + h * 4);
        const f4 v3 = *(const f4*)(brA + j * 16 + h * 4);
        const f32x4 cf = {v1.x, v1.y, v1.z, v1.w};
        const f32x4 cg = {v2.x, v2.y, v2.z, v2.w};
        const f32x4 cr = {v3.x, v3.y, v3.z, v3.w};

        auto tile0 = [&](int l, int n, f32x4& res) {
            const int ns = tap ? n : n - d;
            bf16x8 bx = {0, 0, 0, 0, 0, 0, 0, 0};
            if (cfg.l0) {
                if (ns >= 0) {   // layer-0 output computed on the fly from x
                    const float xs = xrow[ns] * (1.0f / 32768.0f);
                    const float xm = (ns >= 1) ? xrow[ns - 1] * (1.0f / 32768.0f) : 0.0f;
#pragma unroll
                    for (int q2 = 0; q2 < 8; ++q2) {
                        const int c = c0 + q2;
                        bx[q2] = to_bf16(xs + fmaf(W0[c * 2], xm,
                                          fmaf(W0[c * 2 + 1], xs, b0[c])));
                    }
                }
            } else {
                if (ns >= 0) bx = *(const bf16x8*)(srow + (size_t)ns * NC + c0);
            }
            const f32x4 o = gated_core2(bx, af, ag, ar, cf, cg, cr);

            float r0, r1, r2, r3;        // residual input at (n, h*4..h*4+3)
            if (cfg.l0) {
                if (n >= 0) {
                    const float xs = xrow[n] * (1.0f / 32768.0f);
                    const float xm = (n >= 1) ? xrow[n - 1] * (1.0f / 32768.0f) : 0.0f;
                    const int c = h * 4;
                    r0 = xs + fmaf(W0[c * 2 + 0], xm, fmaf(W0[c * 2 + 1], xs, b0[c + 0]));
                    r1 = xs + fmaf(W0[c * 2 + 2], xm, fmaf(W0[c * 2 + 3], xs, b0[c + 1]));
                    r2 = xs + fmaf(W0[c * 2 + 4], xm, fmaf(W0[c * 2 + 5], xs, b0[c + 2]));
                    r3 = xs + fmaf(W0[c * 2 + 6], xm, fmaf(W0[c * 2 + 7], xs, b0[c + 3]));
                } else { r0 = r1 = r2 = r3 = 0.0f; }
            } else {
                if (n >= 0) {
                    const short4 ov = *(const short4*)(srow + (size_t)n * NC + h * 4);
                    r0 = from_bf16(ov.x); r1 = from_bf16(ov.y);
                    r2 = from_bf16(ov.z); r3 = from_bf16(ov.w);
                } else { r0 = r1 = r2 = r3 = 0.0f; }
            }
            res[0] = r0 + o[0]; res[1] = r1 + o[1];
            res[2] = r2 + o[2]; res[3] = r3 + o[3];
            if (MULTI) {
                *(short4*)(ldsA + l * LSTR + h * 4) =
                    make_short4(to_bf16(res[0]), to_bf16(res[1]),
                                to_bf16(res[2]), to_bf16(res[3]));
            }
        };
        tile0(l0r, nA, res0);
        tile0(l1r, nB, res1);
    }
    if (MULTI) __syncthreads();

    // ---- layers 1..nl-1: taps from LDS, residual stays in registers ----
    int cur = 0;
#pragma unroll
    for (int s = 1; s < cfg.nl; ++s) {
        const int d = cfg.d[s];
        const int j = cfg.jbase + s;
        const bf16x8 af = *(const bf16x8*)(pk + OFF_WF + j * 512 + lane * 8);
        const bf16x8 ag = *(const bf16x8*)(pk + OFF_WG + j * 512 + lane * 8);
        const bf16x8 ar = *(const bf16x8*)(pk + OFF_WR + j * 512 + lane * 8);
        const f4 v1 = *(const f4*)(bfA + j * 16 + h * 4);
        const f4 v2 = *(const f4*)(bgA + j * 16 + h * 4);
        const f4 v3 = *(const f4*)(brA + j * 16 + h * 4);
        const f32x4 cf = {v1.x, v1.y, v1.z, v1.w};
        const f32x4 cg = {v2.x, v2.y, v2.z, v2.w};
        const f32x4 cr = {v3.x, v3.y, v3.z, v3.w};
        const short* rb = cur ? ldsB : ldsA;
        short* wb = cur ? ldsA : ldsB;
        const bool wr = (s + 1 < cfg.nl);   // last layer: LDS write is dead

        auto tileL = [&](int l, int n, f32x4& res) {
            const int nt = tap ? n : n - d;
            int lt = tap ? l : l - d;
            if (lt < 0) lt = 0;          // garbage-region clamp (never read clean)
            bf16x8 bx = {0, 0, 0, 0, 0, 0, 0, 0};
            if (nt >= 0) bx = *(const bf16x8*)(rb + lt * LSTR + c0);
            const f32x4 o = gated_core2(bx, af, ag, ar, cf, cg, cr);
            res[0] += o[0]; res[1] += o[1]; res[2] += o[2]; res[3] += o[3];
            if (wr) {
                *(short4*)(wb + l * LSTR + h * 4) =
                    make_short4(to_bf16(res[0]), to_bf16(res[1]),
                                to_bf16(res[2]), to_bf16(res[3]));
            }
        };
        tileL(l0r, nA, res0);
        tileL(l1r, nB, res1);
        if (s + 1 < cfg.nl) __syncthreads();
        cur ^= 1;
    }

    // ---- writeback of owned positions from registers ----
    if (l0r >= H) {
        *(short4*)(dst + ((size_t)bb * NN + nA) * NC + h * 4) =
            make_short4(to_bf16(res0[0]), to_bf16(res0[1]),
                        to_bf16(res0[2]), to_bf16(res0[3]));
    }
    if (l1r >= H) {
        *(short4*)(dst + ((size_t)bb * NN + nB) * NC + h * 4) =
            make_short4(to_bf16(res1[0]), to_bf16(res1[1]),
                        to_bf16(res1[2]), to_bf16(res1[3]));
    }
}

// ---------------- head: fused j26+j27+j28 + 16->64->256 + LSE -----------------
// src = post-j25 stream. Eval tree: j26 at {n, n-256, n-512, n-768} (taps from
// global), j27 at {n, n-512}, j28 at n. All position guards are multiples of
// the 128-pos block -> wave-uniform (MFMA never runs under divergent exec).
// 4-ch/lane -> 8-ch/lane crossovers via per-wave LDS scratch (wave-local).
__global__ __launch_bounds__(512, 2) void headm_k(
    const short* __restrict__ src, const float* __restrict__ x,
    const int* __restrict__ lengths, const short* __restrict__ pk,
    const float* __restrict__ bfL, const float* __restrict__ bgL,
    const float* __restrict__ brL,
    const short* __restrict__ pka, const float* __restrict__ ba,
    const short* __restrict__ pko, const float* __restrict__ bo,
    float* __restrict__ out)
{
    __shared__ short ldsW[16384];            // all Wo fragments, 32 KB
    __shared__ short S26[4][8][256];         // post-j26 at n,-256,-512,-768
    __shared__ short S27[2][8][256];         // post-j27 at n, n-512
    __shared__ short SK[8][256];             // sk

    const int t = threadIdx.x;
    const int lane = t & 63;
    const int wv = t >> 6;
    const int i16 = lane & 15;
    const int h = lane >> 4;
    const int pos = blockIdx.x * 128 + wv * 16 + i16;
    const int b = pos >> 14;
    const int n = pos & (NN - 1);
    const int tap = h >> 1, c0 = (h & 1) * 8;
    const short* srow = src + (size_t)b * NN * NC;

    // cooperative stage of Wo frags: 512 threads x 4 x 16B coalesced
#pragma unroll
    for (int i = 0; i < 4; ++i)
        ((f4*)ldsW)[t + i * 512] = ((const f4*)pko)[t + i * 512];

    // ---- j26 (d=128) at 4 positions, taps/residual from GLOBAL ----
    f32x4 r26a, r26c;                        // fp32 residuals kept for j27
    {
        constexpr int j = NLAY - 3;          // 26
        const bf16x8 af = *(const bf16x8*)(pk + OFF_WF + j * 512 + lane * 8);
        const bf16x8 ag = *(const bf16x8*)(pk + OFF_WG + j * 512 + lane * 8);
        const bf16x8 ar = *(const bf16x8*)(pk + OFF_WR + j * 512 + lane * 8);
        const f4 v1 = *(const f4*)(bfL + j * 16 + h * 4);
        const f4 v2 = *(const f4*)(bgL + j * 16 + h * 4);
        const f4 v3 = *(const f4*)(brL + j * 16 + h * 4);
        const f32x4 cf = {v1.x, v1.y, v1.z, v1.w};
        const f32x4 cg = {v2.x, v2.y, v2.z, v2.w};
        const f32x4 cr = {v3.x, v3.y, v3.z, v3.w};

        auto run26 = [&](int p, short* dstS) -> f32x4 {
            const int ns = tap ? p : p - 128;
            bf16x8 bx = {0, 0, 0, 0, 0, 0, 0, 0};
            if (ns >= 0) bx = *(const bf16x8*)(srow + (size_t)ns * NC + c0);
            const f32x4 o = gated_core2(bx, af, ag, ar, cf, cg, cr);
            const short4 ov = *(const short4*)(srow + (size_t)p * NC + h * 4);
            f32x4 r;
            r[0] = from_bf16(ov.x) + o[0]; r[1] = from_bf16(ov.y) + o[1];
            r[2] = from_bf16(ov.z) + o[2]; r[3] = from_bf16(ov.w) + o[3];
            *(short4*)(dstS + i16 * 16 + h * 4) =
                make_short4(to_bf16(r[0]), to_bf16(r[1]),
                            to_bf16(r[2]), to_bf16(r[3]));
            return r;
        };
        r26a = run26(n, &S26[0][wv][0]);
        if (n >= 256) run26(n - 256, &S26[1][wv][0]);
        if (n >= 512) r26c = run26(n - 512, &S26[2][wv][0]);
        if (n >= 768) run26(n - 768, &S26[3][wv][0]);
    }

    // ---- j27 (d=256) at n and n-512, taps from wave-local scratch ----
    f32x4 r27n;
    {
        constexpr int j = NLAY - 2;          // 27
        const bf16x8 af = *(const bf16x8*)(pk + OFF_WF + j * 512 + lane * 8);
        const bf16x8 ag = *(const bf16x8*)(pk + OFF_WG + j * 512 + lane * 8);
        const bf16x8 ar = *(const bf16x8*)(pk + OFF_WR + j * 512 + lane * 8);
        const f4 v1 = *(const f4*)(bfL + j * 16 + h * 4);
        const f4 v2 = *(const f4*)(bgL + j * 16 + h * 4);
        const f4 v3 = *(const f4*)(brL + j * 16 + h * 4);
        const f32x4 cf = {v1.x, v1.y, v1.z, v1.w};
        const f32x4 cg = {v2.x, v2.y, v2.z, v2.w};
        const f32x4 cr = {v3.x, v3.y, v3.z, v3.w};

        // at n: tap1 = post-j26[n] (S26[0]); tap0 = post-j26[n-256] (S26[1])
        {
            bf16x8 bx = {0, 0, 0, 0, 0, 0, 0, 0};
            if (tap) bx = *(const bf16x8*)(&S26[0][wv][i16 * 16 + c0]);
            else if (n >= 256) bx = *(const bf16x8*)(&S26[1][wv][i16 * 16 + c0]);
            const f32x4 o = gated_core2(bx, af, ag, ar, cf, cg, cr);
            r27n[0] = r26a[0] + o[0]; r27n[1] = r26a[1] + o[1];
            r27n[2] = r26a[2] + o[2]; r27n[3] = r26a[3] + o[3];
            *(short4*)(&S27[0][wv][i16 * 16 + h * 4]) =
                make_short4(to_bf16(r27n[0]), to_bf16(r27n[1]),
                            to_bf16(r27n[2]), to_bf16(r27n[3]));
        }
        // at n-512: tap1 = S26[2]; tap0 = S26[3] (n-768)
        if (n >= 512) {
            bf16x8 bx = {0, 0, 0, 0, 0, 0, 0, 0};
            if (tap) bx = *(const bf16x8*)(&S26[2][wv][i16 * 16 + c0]);
            else if (n >= 768) bx = *(const bf16x8*)(&S26[3][wv][i16 * 16 + c0]);
            const f32x4 o = gated_core2(bx, af, ag, ar, cf, cg, cr);
            *(short4*)(&S27[1][wv][i16 * 16 + h * 4]) = make_short4(
                to_bf16(r26c[0] + o[0]), to_bf16(r26c[1] + o[1]),
                to_bf16(r26c[2] + o[2]), to_bf16(r26c[3] + o[3]));
        }
    }

    // ---- j28 (d=512) at n, taps from wave-local scratch ----
    {
        constexpr int j = NLAY - 1;          // 28
        const bf16x8 af = *(const bf16x8*)(pk + OFF_WF + j * 512 + lane * 8);
        const bf16x8 ag = *(const bf16x8*)(pk + OFF_WG + j * 512 + lane * 8);
        const bf16x8 ar = *(const bf16x8*)(pk + OFF_WR + j * 512 + lane * 8);
        const f4 v1 = *(const f4*)(bfL + j * 16 + h * 4);
        const f4 v2 = *(const f4*)(bgL + j * 16 + h * 4);
        const f4 v3 = *(const f4*)(brL + j * 16 + h * 4);
        const f32x4 cf = {v1.x, v1.y, v1.z, v1.w};
        const f32x4 cg = {v2.x, v2.y, v2.z, v2.w};
        const f32x4 cr = {v3.x, v3.y, v3.z, v3.w};

        bf16x8 bx = {0, 0, 0, 0, 0, 0, 0, 0};
        if (tap) bx = *(const bf16x8*)(&S27[0][wv][i16 * 16 + c0]);
        else if (n >= 512) bx = *(const bf16x8*)(&S27[1][wv][i16 * 16 + c0]);
        const f32x4 o = gated_core2(bx, af, ag, ar, cf, cg, cr);

        const float xs = x[pos] * (1.0f / 32768.0f);
        // sk = relu(fin - xs), fin = r27n + o (fp32)
        *(short4*)(&SK[wv][i16 * 16 + h * 4]) = make_short4(
            to_bf16(fmaxf(r27n[0] + o[0] - xs, 0.0f)),
            to_bf16(fmaxf(r27n[1] + o[1] - xs, 0.0f)),
            to_bf16(fmaxf(r27n[2] + o[2] - xs, 0.0f)),
            to_bf16(fmaxf(r27n[3] + o[3] - xs, 0.0f)));
    }

    // B fragment for Wa: sk channels k=h*8+j (real for h<2) from scratch
    bf16x8 bs;
    if (h < 2) {
        bs = *(const bf16x8*)(&SK[wv][i16 * 16 + h * 8]);
    } else {
#pragma unroll
        for (int j = 0; j < 8; ++j) bs[j] = 0;
    }

    // Wa GEMM: ra = relu(...), 16 values/lane, lane-local for Wo B-frags
    float ra[16];
#pragma unroll
    for (int mt = 0; mt < 4; ++mt) {
        const bf16x8 aa = *(const bf16x8*)(pka + (mt * 64 + lane) * 8);
        const f4 bav = *(const f4*)(ba + mt * 16 + h * 4);
        f32x4 c = {bav.x, bav.y, bav.z, bav.w};
        c = __builtin_amdgcn_mfma_f32_16x16x32_bf16(aa, bs, c, 0, 0, 0);
#pragma unroll
        for (int r = 0; r < 4; ++r) ra[mt * 4 + r] = fmaxf(c[r], 0.0f);
    }
    bf16x8 blo, bhi;
#pragma unroll
    for (int j = 0; j < 8; ++j) { blo[j] = to_bf16(ra[j]); bhi[j] = to_bf16(ra[8 + j]); }

    __syncthreads();   // Wo frags staged (ldsW)

    // Wo GEMM: 16 q-tiles x (2 MFMA, K=64); A-frags from LDS; logits in VGPRs
    float lg[64];
#pragma unroll
    for (int qt = 0; qt < 16; ++qt) {
        const bf16x8 a0 = *(const bf16x8*)(ldsW + ((qt * 2 + 0) * 64 + lane) * 8);
        const bf16x8 a1 = *(const bf16x8*)(ldsW + ((qt * 2 + 1) * 64 + lane) * 8);
        const f4 bov = *(const f4*)(bo + qt * 16 + h * 4);
        f32x4 c = {bov.x, bov.y, bov.z, bov.w};
        c = __builtin_amdgcn_mfma_f32_16x16x32_bf16(a0, blo, c, 0, 0, 0);
        c = __builtin_amdgcn_mfma_f32_16x16x32_bf16(a1, bhi, c, 0, 0, 0);
#pragma unroll
        for (int r = 0; r < 4; ++r) lg[qt * 4 + r] = c[r];
    }

    // LSE across lanes {i, i+16, i+32, i+48}
    float m = lg[0];
#pragma unroll
    for (int j = 1; j < 64; ++j) m = fmaxf(m, lg[j]);
    m = fmaxf(m, __shfl_xor(m, 16, 64));
    m = fmaxf(m, __shfl_xor(m, 32, 64));
    float s = 0.0f;
#pragma unroll
    for (int j = 0; j < 64; ++j) s += __expf(lg[j] - m);
    s += __shfl_xor(s, 16, 64);
    s += __shfl_xor(s, 32, 64);
    const float lse = m + __logf(s);
    const bool valid = n < lengths[b];

    // write: q = qt*16 + h*4 + r at out[b][q][n] (full 64B lines per h-group)
    float* ob = out + (size_t)b * 256 * NN + n;
#pragma unroll
    for (int qt = 0; qt < 16; ++qt)
#pragma unroll
        for (int r = 0; r < 4; ++r)
            ob[(size_t)(qt * 16 + h * 4 + r) * NN] = valid ? (lg[qt * 4 + r] - lse) : 0.0f;
}

extern "C" void kernel_launch(void* const* d_in, const int* in_sizes, int n_in,
                              void* d_out, int out_size, void* d_ws, size_t ws_size,
                              hipStream_t stream)
{
    const float* x       = (const float*)d_in[0];
    const int*   lengths = (const int*)d_in[1];
    const float* W0      = (const float*)d_in[2];
    const float* b0      = (const float*)d_in[3];
    const float* Wf      = (const float*)d_in[4];
    const float* bf      = (const float*)d_in[5];
    const float* Wg      = (const float*)d_in[6];
    const float* bg      = (const float*)d_in[7];
    const float* Wr      = (const float*)d_in[8];
    const float* br      = (const float*)d_in[9];
    const float* Wa      = (const float*)d_in[10];
    const float* ba      = (const float*)d_in[11];
    const float* Wo      = (const float*)d_in[12];
    const float* bo      = (const float*)d_in[13];
    float* out = (float*)d_out;

    short* bufA = (short*)d_ws;                         // (B,N,16) bf16, 4.2 MB
    short* bufB = bufA + (size_t)NPOSTOT * NC;
    short* pk   = bufB + (size_t)NPOSTOT * NC;          // packed weight frags

    prepack_k<<<dim3((PK_TOT + 255) / 256), dim3(256), 0, stream>>>(
        Wf, Wg, Wr, Wa, Wo, pk);

#define FUSED(K, SRC, DST)                                                     \
    fused_t<K><<<dim3(NPOSTOT / TOUT), dim3((TOUT + CFGS[K].H) * 2), 0,        \
                 stream>>>(SRC, x, W0, b0, DST, pk, bf, bg, br)

    FUSED(0, bufA, bufA);   // src unused (l0 mode)
    FUSED(1, bufA, bufB);
    FUSED(2, bufB, bufA);
    FUSED(3, bufA, bufB);
    FUSED(4, bufB, bufA);   // K4 -> bufA (post-j25)
#undef FUSED

    // head consumes post-j25 (bufA), fuses j26 + j27 + j28 inline
    headm_k<<<dim3(NPOSTOT / 128), dim3(512), 0, stream>>>(
        bufA, x, lengths, pk, bf, bg, br,
        pk + OFF_WA, ba, pk + OFF_WO, bo, out);
}